// Round 1
// baseline (2041.905 us; speedup 1.0000x reference)
//
#include <hip/hip_runtime.h>
#include <hip/hip_bf16.h>
#include <cstdint>
#include <cstddef>

#define DEVINL __device__ __forceinline__

typedef _Float16 f16x8 __attribute__((ext_vector_type(8)));
typedef float    f32x4 __attribute__((ext_vector_type(4)));

// problem constants
// B=4, T=256, U=64, E=H=J=512, O=1024, gate rows 2048

DEVINL float fsigm(float x) {
    float e = __expf(-x);
    return __builtin_amdgcn_rcpf(1.f + e);
}
DEVINL float ftanh(float x) {
    float e = __expf(2.f * x);
    return 1.f - 2.f * __builtin_amdgcn_rcpf(e + 1.f);
}

// ---------------------------------------------------------------------------
// prep: cast LSTM weights + W_out to f16 into ws
// layout in dst (elements): [Wih0 1M | Whh0 1M | Wih1 1M | Whh1 1M | Wout 0.5M]
// ---------------------------------------------------------------------------
__global__ void k_prep_f16(const float* __restrict__ wih0, const float* __restrict__ whh0,
                           const float* __restrict__ wih1, const float* __restrict__ whh1,
                           const float* __restrict__ wout, _Float16* __restrict__ dst, int total) {
    int stride = gridDim.x * blockDim.x;
    for (int i = blockIdx.x * blockDim.x + threadIdx.x; i < total; i += stride) {
        const float* src; int off;
        if      (i < (1 << 20)) { src = wih0; off = i; }
        else if (i < (2 << 20)) { src = whh0; off = i - (1 << 20); }
        else if (i < (3 << 20)) { src = wih1; off = i - (2 << 20); }
        else if (i < (4 << 20)) { src = whh1; off = i - (3 << 20); }
        else                    { src = wout; off = i - (4 << 20); }
        dst[i] = (_Float16)src[off];
    }
}

// ---------------------------------------------------------------------------
// embedding gather: Ebuf[(u*4+b)*512 + e] = embed[ys_in[b][u]][e]
// ---------------------------------------------------------------------------
__global__ void k_embed(const float* __restrict__ embed, const int* __restrict__ ys,
                        float* __restrict__ Ebuf) {
    int bu = blockIdx.x;           // 0..255
    int b = bu >> 6, u = bu & 63;
    int tok = (u == 0) ? 0 : ys[b * 63 + (u - 1)];
    const float* src = embed + (size_t)tok * 512;
    float* dst = Ebuf + ((size_t)(u * 4 + b)) * 512;
    int t2 = threadIdx.x * 2;
    float2 v = *(const float2*)(src + t2);
    *(float2*)(dst + t2) = v;
}

// ---------------------------------------------------------------------------
// persistent 2-layer LSTM. grid = 256 blocks x 256 threads.
// blocks 0..127: layer0, 128..255: layer1 (lagging one super-step).
// block blk owns 4 hidden units (hu0 = blk*4): 16 gate rows x 4 batches = 64
// outputs, 4 threads per output (e-quarters of the 1024-dim [x|h] dot).
// Cross-block h via agent-scope atomics; barrier = atomic counter per step.
// ---------------------------------------------------------------------------
__global__ void __launch_bounds__(256, 1) k_lstm(
        const _Float16* __restrict__ WF,
        const float* __restrict__ bih0, const float* __restrict__ bhh0,
        const float* __restrict__ bih1, const float* __restrict__ bhh1,
        const float* __restrict__ Ebuf, float* __restrict__ H0,
        float* __restrict__ H1, int* __restrict__ bar) {
    const int blk   = blockIdx.x & 127;
    const int layer = blockIdx.x >> 7;
    const int tid   = threadIdx.x;
    const int oi    = tid & 63;      // output id: b = oi&3, r16 = oi>>2
    const int quarter = tid >> 6;    // e-range quarter
    const int b   = oi & 3;
    const int r16 = oi >> 2;         // 0..15 : gate g = r16>>2, unit j = r16&3
    const int g   = r16 >> 2;
    const int jj  = r16 & 3;
    const int hu  = blk * 4 + jj;
    const int row = g * 512 + hu;    // gate row in [0,2048)

    const _Float16* Wih = WF + (size_t)layer * (2u << 20);
    const _Float16* Whh = Wih + (1u << 20);
    const float* bi = layer ? bih1 : bih0;
    const float* bh = layer ? bhh1 : bhh0;

    __shared__ float xh[4 * 1028];   // padded stride 1028 (bank decorrelation)
    __shared__ float red[256];
    __shared__ float gates[64];

    float c_reg = 0.f;

    const int e0 = quarter * 256;
    const _Float16* wptr = (e0 < 512) ? (Wih + (size_t)row * 512 + e0)
                                      : (Whh + (size_t)row * 512 + (e0 - 512));

    for (int s = 0; s <= 64; ++s) {
        if (s > 0) {
            if (tid == 0) {
                while (__hip_atomic_load(bar + (s - 1), __ATOMIC_ACQUIRE,
                                         __HIP_MEMORY_SCOPE_AGENT) < 256) {
                    __builtin_amdgcn_s_sleep(1);
                }
            }
            __syncthreads();
        }
        const bool active = (layer == 0) ? (s < 64) : (s >= 1);
        const int st = (layer == 0) ? s : (s - 1);
        if (active) {
            // stage [x|h] (4 x 1024) into LDS, 16 values per thread
            {
                int q0 = tid * 16;
                int bb = q0 >> 10;
                int ee = q0 & 1023;
                float* dst = xh + bb * 1028 + ee;
                if (ee < 512) {
                    if (layer == 0) {
                        const float* src = Ebuf + ((size_t)(st * 4 + bb)) * 512 + ee;
                        #pragma unroll
                        for (int i = 0; i < 4; ++i)
                            ((float4*)dst)[i] = ((const float4*)src)[i];
                    } else {
                        const float* src = H0 + ((size_t)(st * 4 + bb)) * 512 + ee;
                        #pragma unroll
                        for (int i = 0; i < 16; ++i)
                            dst[i] = __hip_atomic_load(src + i, __ATOMIC_RELAXED,
                                                       __HIP_MEMORY_SCOPE_AGENT);
                    }
                } else {
                    int he = ee - 512;
                    if (st == 0) {
                        #pragma unroll
                        for (int i = 0; i < 16; ++i) dst[i] = 0.f;
                    } else {
                        const float* src = (layer == 0)
                            ? (H0 + ((size_t)((st - 1) * 4 + bb)) * 512 + he)
                            : (H1 + ((size_t)(bb * 64 + (st - 1))) * 512 + he);
                        #pragma unroll
                        for (int i = 0; i < 16; ++i)
                            dst[i] = __hip_atomic_load(src + i, __ATOMIC_RELAXED,
                                                       __HIP_MEMORY_SCOPE_AGENT);
                    }
                }
            }
            __syncthreads();
            // partial dot: 256 MACs over e0..e0+255 (weights from global/L1, f16)
            float acc = 0.f;
            const float* xv = xh + b * 1028 + e0;
            #pragma unroll 8
            for (int i = 0; i < 32; ++i) {
                f16x8 w8 = *(const f16x8*)(wptr + i * 8);
                float4 x0 = *(const float4*)(xv + i * 8);
                float4 x1 = *(const float4*)(xv + i * 8 + 4);
                acc += (float)w8[0] * x0.x + (float)w8[1] * x0.y +
                       (float)w8[2] * x0.z + (float)w8[3] * x0.w +
                       (float)w8[4] * x1.x + (float)w8[5] * x1.y +
                       (float)w8[6] * x1.z + (float)w8[7] * x1.w;
            }
            red[tid] = acc;
            __syncthreads();
            if (tid < 64) {
                gates[tid] = red[tid] + red[tid + 64] + red[tid + 128] + red[tid + 192]
                           + bi[row] + bh[row];
            }
            __syncthreads();
            if (tid < 16) {
                int j2 = tid >> 2, b2 = tid & 3;
                float gi = gates[(0 + j2) * 4 + b2];
                float gf = gates[(4 + j2) * 4 + b2];
                float gg = gates[(8 + j2) * 4 + b2];
                float go = gates[(12 + j2) * 4 + b2];
                c_reg = fsigm(gf) * c_reg + fsigm(gi) * ftanh(gg);
                float h2 = fsigm(go) * ftanh(c_reg);
                int hu2 = blk * 4 + j2;
                if (layer == 0)
                    __hip_atomic_store(H0 + ((size_t)(st * 4 + b2)) * 512 + hu2, h2,
                                       __ATOMIC_RELAXED, __HIP_MEMORY_SCOPE_AGENT);
                else
                    __hip_atomic_store(H1 + ((size_t)(b2 * 64 + st)) * 512 + hu2, h2,
                                       __ATOMIC_RELAXED, __HIP_MEMORY_SCOPE_AGENT);
            }
        }
        __syncthreads();   // drains vmcnt: all stores of this block complete
        if (tid == 0)
            __hip_atomic_fetch_add(bar + s, 1, __ATOMIC_RELEASE,
                                   __HIP_MEMORY_SCOPE_AGENT);
    }
}

// ---------------------------------------------------------------------------
// small fp32 GEMM: C[m][n] = bias[n] + sum_k A[m][k]*Bt[n][k];  N=K=512.
// 64x64 tile per block, 16x16 threads, 4x4 outs (rows/cols strided by 16).
// grid.x = (M/64)*8
// ---------------------------------------------------------------------------
__global__ void __launch_bounds__(256) k_gemm_small(
        const float* __restrict__ A, const float* __restrict__ Bt,
        const float* __restrict__ bias, float* __restrict__ C) {
    __shared__ float As[64 * 68];
    __shared__ float Bs[64 * 68];
    int bn = blockIdx.x & 7;
    int bm = blockIdx.x >> 3;
    int m0 = bm * 64, n0 = bn * 64;
    int tid = threadIdx.x;
    int tx = tid & 15, ty = tid >> 4;
    float acc[4][4] = {};
    for (int k0 = 0; k0 < 512; k0 += 64) {
        __syncthreads();
        #pragma unroll
        for (int i = 0; i < 4; ++i) {
            int fid = i * 256 + tid;            // 1024 float4 per tile
            int r = fid >> 4, c4 = (fid & 15) * 4;
            *(float4*)(As + r * 68 + c4) = *(const float4*)(A + (size_t)(m0 + r) * 512 + k0 + c4);
            *(float4*)(Bs + r * 68 + c4) = *(const float4*)(Bt + (size_t)(n0 + r) * 512 + k0 + c4);
        }
        __syncthreads();
        #pragma unroll 4
        for (int kk = 0; kk < 64; kk += 4) {
            float4 a4[4], b4[4];
            #pragma unroll
            for (int ii = 0; ii < 4; ++ii) a4[ii] = *(const float4*)(As + (ty + ii * 16) * 68 + kk);
            #pragma unroll
            for (int jjx = 0; jjx < 4; ++jjx) b4[jjx] = *(const float4*)(Bs + (tx + jjx * 16) * 68 + kk);
            #pragma unroll
            for (int ii = 0; ii < 4; ++ii)
                #pragma unroll
                for (int jjx = 0; jjx < 4; ++jjx)
                    acc[ii][jjx] += a4[ii].x * b4[jjx].x + a4[ii].y * b4[jjx].y +
                                    a4[ii].z * b4[jjx].z + a4[ii].w * b4[jjx].w;
        }
    }
    #pragma unroll
    for (int ii = 0; ii < 4; ++ii) {
        int m = m0 + ty + ii * 16;
        #pragma unroll
        for (int jjx = 0; jjx < 4; ++jjx) {
            int n = n0 + tx + jjx * 16;
            float v = acc[ii][jjx] + (bias ? bias[n] : 0.f);
            C[(size_t)m * 512 + n] = v;
        }
    }
}

// ---------------------------------------------------------------------------
// joint: out[m][n] = b_out[n] + sum_k tanh(henc[b,t,k]+hdec[b,u,k]) * Wo[n][k]
// m = b*16384 + t*64 + u; M=65536, N=1024, K=512.
// 128x128 tile, BK=64, f16 MFMA 16x16x32, 4 waves 2x2, 4x4 accs each.
// ---------------------------------------------------------------------------
__global__ void __launch_bounds__(256) k_joint(
        const float* __restrict__ henc, const float* __restrict__ hdec,
        const _Float16* __restrict__ Wo, const float* __restrict__ b_out,
        float* __restrict__ out) {
    __shared__ _Float16 As[128 * 72];   // rows padded 64->72 (2-way only)
    __shared__ _Float16 Bs[128 * 72];

    const int bn = blockIdx.x & 7;
    const int bm = blockIdx.x >> 3;
    const int m0 = bm * 128, n0 = bn * 128;
    const int b  = m0 >> 14;
    const int t0 = (m0 & 16383) >> 6;   // tile covers t0, t0+1 (u fast)

    const int tid  = threadIdx.x;
    const int wave = tid >> 6, lane = tid & 63;
    const int wm = wave >> 1, wn = wave & 1;
    const int l16 = lane & 15, quad = lane >> 4;

    // A-generation mapping: thread -> (tile row, k-half)
    const int r_gen = tid >> 1;         // 0..127
    const int half  = tid & 1;          // k-offset 0 / 32
    const int tg = r_gen >> 6, ug = r_gen & 63;
    const float* he_row = henc + ((size_t)(b * 256 + t0 + tg)) * 512 + half * 32;
    const float* hd_row = hdec + ((size_t)(b * 64 + ug)) * 512 + half * 32;
    _Float16* As_row = As + r_gen * 72 + half * 32;

    f32x4 acc[4][4];
    #pragma unroll
    for (int i = 0; i < 4; ++i)
        #pragma unroll
        for (int j = 0; j < 4; ++j) acc[i][j] = f32x4{0.f, 0.f, 0.f, 0.f};

    for (int kit = 0; kit < 8; ++kit) {
        const int k0 = kit * 64;
        __syncthreads();
        // generate A tile: z = tanh(henc + hdec) -> f16
        #pragma unroll
        for (int i2 = 0; i2 < 4; ++i2) {
            float4 a  = *(const float4*)(he_row + k0 + i2 * 8);
            float4 c  = *(const float4*)(hd_row + k0 + i2 * 8);
            float4 a2 = *(const float4*)(he_row + k0 + i2 * 8 + 4);
            float4 c2 = *(const float4*)(hd_row + k0 + i2 * 8 + 4);
            f16x8 z8;
            z8[0] = (_Float16)ftanh(a.x + c.x);
            z8[1] = (_Float16)ftanh(a.y + c.y);
            z8[2] = (_Float16)ftanh(a.z + c.z);
            z8[3] = (_Float16)ftanh(a.w + c.w);
            z8[4] = (_Float16)ftanh(a2.x + c2.x);
            z8[5] = (_Float16)ftanh(a2.y + c2.y);
            z8[6] = (_Float16)ftanh(a2.z + c2.z);
            z8[7] = (_Float16)ftanh(a2.w + c2.w);
            *(f16x8*)(As_row + i2 * 8) = z8;
        }
        // stage B tile: Wo rows n0..n0+128, cols k0..k0+64
        #pragma unroll
        for (int j2 = 0; j2 < 4; ++j2) {
            int q = j2 * 256 + tid;
            int r = q >> 3, c8 = q & 7;
            f16x8 w = *(const f16x8*)(Wo + (size_t)(n0 + r) * 512 + k0 + c8 * 8);
            *(f16x8*)(Bs + r * 72 + c8 * 8) = w;
        }
        __syncthreads();
        // MFMA over the two k-32 steps of this BK=64 chunk
        #pragma unroll
        for (int kk = 0; kk < 64; kk += 32) {
            f16x8 af[4], bfv[4];
            #pragma unroll
            for (int i = 0; i < 4; ++i)
                af[i] = *(const f16x8*)(As + (wm * 64 + i * 16 + l16) * 72 + kk + quad * 8);
            #pragma unroll
            for (int j = 0; j < 4; ++j)
                bfv[j] = *(const f16x8*)(Bs + (wn * 64 + j * 16 + l16) * 72 + kk + quad * 8);
            #pragma unroll
            for (int i = 0; i < 4; ++i)
                #pragma unroll
                for (int j = 0; j < 4; ++j)
                    acc[i][j] = __builtin_amdgcn_mfma_f32_16x16x32_f16(af[i], bfv[j], acc[i][j], 0, 0, 0);
        }
    }
    // epilogue: C/D layout col=lane&15, row=quad*4+reg
    #pragma unroll
    for (int i = 0; i < 4; ++i) {
        int mrow = m0 + wm * 64 + i * 16 + quad * 4;
        #pragma unroll
        for (int j = 0; j < 4; ++j) {
            int col = n0 + wn * 64 + j * 16 + l16;
            float bo = b_out[col];
            float* po = out + (size_t)mrow * 1024 + col;
            po[0]              = acc[i][j][0] + bo;
            po[1024]           = acc[i][j][1] + bo;
            po[2048]           = acc[i][j][2] + bo;
            po[3072]           = acc[i][j][3] + bo;
        }
    }
}

// ---------------------------------------------------------------------------
extern "C" void kernel_launch(void* const* d_in, const int* in_sizes, int n_in,
                              void* d_out, int out_size, void* d_ws, size_t ws_size,
                              hipStream_t stream) {
    const float* hs    = (const float*)d_in[0];
    const int*   ys    = (const int*)d_in[2];
    const float* embed = (const float*)d_in[3];
    const float* wih0  = (const float*)d_in[4];
    const float* whh0  = (const float*)d_in[5];
    const float* bih0  = (const float*)d_in[6];
    const float* bhh0  = (const float*)d_in[7];
    const float* wih1  = (const float*)d_in[8];
    const float* whh1  = (const float*)d_in[9];
    const float* bih1  = (const float*)d_in[10];
    const float* bhh1  = (const float*)d_in[11];
    const float* wenc  = (const float*)d_in[12];
    const float* benc  = (const float*)d_in[13];
    const float* wdec  = (const float*)d_in[14];
    const float* wout  = (const float*)d_in[15];
    const float* bout  = (const float*)d_in[16];
    float* out = (float*)d_out;

    char* ws = (char*)d_ws;
    _Float16* WF = (_Float16*)(ws);                         // 9 MB (4x2MB + 1MB)
    float* Ebuf  = (float*)(ws + 9u  * 1024 * 1024);         // 512 KB
    float* H0    = (float*)(ws + 9u  * 1024 * 1024 + 512 * 1024);
    float* H1    = (float*)(ws + 10u * 1024 * 1024);
    float* henc  = (float*)(ws + 10u * 1024 * 1024 + 512 * 1024);  // 2 MB
    float* hdec  = (float*)(ws + 12u * 1024 * 1024 + 512 * 1024);  // 512 KB
    int*   bar   = (int*)  (ws + 13u * 1024 * 1024);

    hipMemsetAsync(bar, 0, 512, stream);
    k_prep_f16<<<2048, 256, 0, stream>>>(wih0, whh0, wih1, whh1, wout, WF, 4718592);
    k_embed<<<256, 256, 0, stream>>>(embed, ys, Ebuf);
    k_lstm<<<256, 256, 0, stream>>>(WF, bih0, bhh0, bih1, bhh1, Ebuf, H0, H1, bar);
    k_gemm_small<<<128, 256, 0, stream>>>(hs, wenc, benc, henc);      // M=1024
    k_gemm_small<<<32, 256, 0, stream>>>(H1, wdec, nullptr, hdec);    // M=256
    k_joint<<<4096, 256, 0, stream>>>(henc, hdec, WF + (4u << 20), bout, out);
}

// Round 2
// 1274.220 us; speedup vs baseline: 1.6025x; 1.6025x over previous
//
#include <hip/hip_runtime.h>
#include <hip/hip_bf16.h>
#include <cstdint>
#include <cstddef>

#define DEVINL __device__ __forceinline__

typedef _Float16 f16x8 __attribute__((ext_vector_type(8)));
typedef _Float16 f16x2 __attribute__((ext_vector_type(2)));
typedef float    f32x4 __attribute__((ext_vector_type(4)));

// B=4, T=256, U=64, E=H=J=512, O=1024, gate rows 2048

DEVINL float fsigm(float x) {
    float e = __expf(-x);
    return __builtin_amdgcn_rcpf(1.f + e);
}
DEVINL float ftanh(float x) {
    float e = __expf(2.f * x);
    return 1.f - 2.f * __builtin_amdgcn_rcpf(e + 1.f);
}

DEVINL float dot8(f16x8 w, f16x8 x, float acc) {
    f16x2 w0{w[0], w[1]}, w1{w[2], w[3]}, w2{w[4], w[5]}, w3{w[6], w[7]};
    f16x2 x0{x[0], x[1]}, x1{x[2], x[3]}, x2{x[4], x[5]}, x3{x[6], x[7]};
    acc = __builtin_amdgcn_fdot2(w0, x0, acc, false);
    acc = __builtin_amdgcn_fdot2(w1, x1, acc, false);
    acc = __builtin_amdgcn_fdot2(w2, x2, acc, false);
    acc = __builtin_amdgcn_fdot2(w3, x3, acc, false);
    return acc;
}

// ---------------------------------------------------------------------------
// prep: cast LSTM weights + W_out to f16
// dst layout (elements): [Wih0 1M | Whh0 1M | Wih1 1M | Whh1 1M | Wout 0.5M]
// ---------------------------------------------------------------------------
__global__ void k_prep_f16(const float* __restrict__ wih0, const float* __restrict__ whh0,
                           const float* __restrict__ wih1, const float* __restrict__ whh1,
                           const float* __restrict__ wout, _Float16* __restrict__ dst, int total) {
    int stride = gridDim.x * blockDim.x;
    for (int i = blockIdx.x * blockDim.x + threadIdx.x; i < total; i += stride) {
        const float* src; int off;
        if      (i < (1 << 20)) { src = wih0; off = i; }
        else if (i < (2 << 20)) { src = whh0; off = i - (1 << 20); }
        else if (i < (3 << 20)) { src = wih1; off = i - (2 << 20); }
        else if (i < (4 << 20)) { src = whh1; off = i - (3 << 20); }
        else                    { src = wout; off = i - (4 << 20); }
        dst[i] = (_Float16)src[off];
    }
}

// ---------------------------------------------------------------------------
// embedding gather (f16 output): Ebuf[(u*4+b)*512 + e] = embed[ys_in[b][u]][e]
// ---------------------------------------------------------------------------
__global__ void k_embed(const float* __restrict__ embed, const int* __restrict__ ys,
                        _Float16* __restrict__ Ebuf) {
    int bu = blockIdx.x;           // 0..255
    int b = bu >> 6, u = bu & 63;
    int tok = (u == 0) ? 0 : ys[b * 63 + (u - 1)];
    const float* src = embed + (size_t)tok * 512;
    _Float16* dst = Ebuf + ((size_t)(u * 4 + b)) * 512;
    int t2 = threadIdx.x * 2;
    float2 v = *(const float2*)(src + t2);
    dst[t2]     = (_Float16)v.x;
    dst[t2 + 1] = (_Float16)v.y;
}

// ---------------------------------------------------------------------------
// persistent 2-layer LSTM. 64 blocks x 256 threads.
// blocks 0..31: layer0, 32..63: layer1 (lagging one round).
// Block owns 16 hidden units -> 64 gate rows x 4 batches.
// Thread (r, kq): r = tid>>2 gate row (g=r>>4, j=r&15), kq = tid&3 selects
// interleaved k8-chunks (k8 = i*4+kq) of the 1024-dim [x|h] dot.
// Barrier: distributed flags (flag[blk] = round+1, release store; wave0
// polls all 64 flags with one lane-parallel load + ballot). No RMW hotspot.
// ---------------------------------------------------------------------------
__global__ void __launch_bounds__(256, 1) k_lstm(
        const _Float16* __restrict__ WF,
        const float* __restrict__ bih0, const float* __restrict__ bhh0,
        const float* __restrict__ bih1, const float* __restrict__ bhh1,
        const _Float16* __restrict__ Ebuf, float* __restrict__ H0,
        float* __restrict__ H1, int* __restrict__ flags) {
    const int blk   = blockIdx.x;
    const int layer = blk >> 5;
    const int ublk  = blk & 31;
    const int unit0 = ublk * 16;
    const int tid   = threadIdx.x;
    const int r     = tid >> 2;          // 0..63 gate row within block
    const int kq    = tid & 3;           // k-interleave phase
    const int g     = r >> 4;
    const int j     = r & 15;
    const int grow  = g * 512 + unit0 + j;   // global gate row 0..2047

    const _Float16* Wih = WF + (size_t)layer * (2u << 20);
    const _Float16* Whh = Wih + (1u << 20);
    const float* bi = layer ? bih1 : bih0;
    const float* bh = layer ? bhh1 : bhh0;
    const _Float16* wih_row = Wih + (size_t)grow * 512;
    const _Float16* whh_row = Whh + (size_t)grow * 512;

    __shared__ _Float16 xh[4 * 1024];    // 4 batches x [x(512) | h(512)] f16
    __shared__ float red[64 * 16];       // partials [r][kq][b]
    __shared__ float g_lds[64 * 4];      // gates [r][b]

    float c_reg = 0.f;

    for (int s = 0; s <= 64; ++s) {
        if (s > 0) {
            if (tid < 64) {
                for (;;) {
                    int f = __hip_atomic_load(flags + tid * 16, __ATOMIC_ACQUIRE,
                                              __HIP_MEMORY_SCOPE_AGENT);
                    if (__ballot(f < s) == 0ull) break;
                    __builtin_amdgcn_s_sleep(1);
                }
            }
            __syncthreads();
        }
        const bool active = (layer == 0) ? (s < 64) : (s >= 1);
        const int st = (layer == 0) ? s : (s - 1);
        if (active) {
            // ---- stage [x|h] into LDS (f16) ----
            if (layer == 0) {
                // x-half from Ebuf (f16, contiguous): 8 f16 per thread
                f16x8 v = *(const f16x8*)(Ebuf + (size_t)st * 2048 + tid * 8);
                int b = tid >> 6, e = (tid * 8) & 511;
                *(f16x8*)(xh + b * 1024 + e) = v;
                // h-half from H0[st-1] (f32, atomic coalesced)
                #pragma unroll
                for (int i = 0; i < 8; ++i) {
                    int el = tid + i * 256;          // 0..2047
                    int bb = el >> 9, he = el & 511;
                    float hv = 0.f;
                    if (st > 0)
                        hv = __hip_atomic_load(H0 + (size_t)(st - 1) * 2048 + el,
                                               __ATOMIC_RELAXED, __HIP_MEMORY_SCOPE_AGENT);
                    xh[bb * 1024 + 512 + he] = (_Float16)hv;
                }
            } else {
                // x-half from H0[st] (f32, atomic coalesced)
                #pragma unroll
                for (int i = 0; i < 8; ++i) {
                    int el = tid + i * 256;
                    int bb = el >> 9, ee = el & 511;
                    float xv = __hip_atomic_load(H0 + (size_t)st * 2048 + el,
                                                 __ATOMIC_RELAXED, __HIP_MEMORY_SCOPE_AGENT);
                    xh[bb * 1024 + ee] = (_Float16)xv;
                }
                // h-half from H1[st-1] (layout [(b*64+u)*512 + unit])
                #pragma unroll
                for (int i = 0; i < 8; ++i) {
                    int el = tid + i * 256;
                    int bb = el >> 9, he = el & 511;
                    float hv = 0.f;
                    if (st > 0)
                        hv = __hip_atomic_load(H1 + ((size_t)(bb * 64 + st - 1)) * 512 + he,
                                               __ATOMIC_RELAXED, __HIP_MEMORY_SCOPE_AGENT);
                    xh[bb * 1024 + 512 + he] = (_Float16)hv;
                }
            }
            __syncthreads();

            // ---- partial dots: thread covers k8 = i*4+kq, all 4 batches ----
            float pb[4] = {0.f, 0.f, 0.f, 0.f};
            #pragma unroll 4
            for (int i = 0; i < 16; ++i) {
                int k8 = i * 4 + kq;
                f16x8 w8 = *(const f16x8*)(wih_row + k8 * 8);
                #pragma unroll
                for (int b2 = 0; b2 < 4; ++b2) {
                    f16x8 x8 = *(const f16x8*)(xh + b2 * 1024 + k8 * 8);
                    pb[b2] = dot8(w8, x8, pb[b2]);
                }
            }
            #pragma unroll 4
            for (int i = 16; i < 32; ++i) {
                int k8 = i * 4 + kq;
                f16x8 w8 = *(const f16x8*)(whh_row + (k8 - 64) * 8);
                #pragma unroll
                for (int b2 = 0; b2 < 4; ++b2) {
                    f16x8 x8 = *(const f16x8*)(xh + b2 * 1024 + k8 * 8);
                    pb[b2] = dot8(w8, x8, pb[b2]);
                }
            }
            float4 pv = {pb[0], pb[1], pb[2], pb[3]};
            *(float4*)(red + ((r * 4 + kq) << 2)) = pv;
            __syncthreads();

            // ---- reduce kq partials -> gates[r][b] ----
            {
                int r2 = tid >> 2, b3 = tid & 3;
                int gr = g * 0 + (r2 >> 4) * 512 + unit0 + (r2 & 15); // global row for r2
                float gval = red[r2 * 16 + b3] + red[r2 * 16 + 4 + b3] +
                             red[r2 * 16 + 8 + b3] + red[r2 * 16 + 12 + b3] +
                             bi[gr] + bh[gr];
                g_lds[r2 * 4 + b3] = gval;
            }
            __syncthreads();

            // ---- activations + h/c update (64 outputs) ----
            if (tid < 64) {
                int jj = tid >> 2, b4 = tid & 3;
                float gi = g_lds[(0  + jj) * 4 + b4];
                float gf = g_lds[(16 + jj) * 4 + b4];
                float gg = g_lds[(32 + jj) * 4 + b4];
                float go = g_lds[(48 + jj) * 4 + b4];
                c_reg = fsigm(gf) * c_reg + fsigm(gi) * ftanh(gg);
                float h2 = fsigm(go) * ftanh(c_reg);
                int hu = unit0 + jj;
                if (layer == 0)
                    __hip_atomic_store(H0 + (size_t)(st * 4 + b4) * 512 + hu, h2,
                                       __ATOMIC_RELAXED, __HIP_MEMORY_SCOPE_AGENT);
                else
                    __hip_atomic_store(H1 + ((size_t)(b4 * 64 + st)) * 512 + hu, h2,
                                       __ATOMIC_RELAXED, __HIP_MEMORY_SCOPE_AGENT);
            }
        }
        __syncthreads();   // all h stores of this block complete (vmcnt drained)
        if (tid == 0)
            __hip_atomic_store(flags + blk * 16, s + 1, __ATOMIC_RELEASE,
                               __HIP_MEMORY_SCOPE_AGENT);
    }
}

// ---------------------------------------------------------------------------
// small fp32 GEMM: C[m][n] = bias[n] + sum_k A[m][k]*Bt[n][k];  N=K=512.
// 64x64 tile per block; grid.x = (M/64)*8
// ---------------------------------------------------------------------------
__global__ void __launch_bounds__(256) k_gemm_small(
        const float* __restrict__ A, const float* __restrict__ Bt,
        const float* __restrict__ bias, float* __restrict__ C) {
    __shared__ float As[64 * 68];
    __shared__ float Bs[64 * 68];
    int bn = blockIdx.x & 7;
    int bm = blockIdx.x >> 3;
    int m0 = bm * 64, n0 = bn * 64;
    int tid = threadIdx.x;
    int tx = tid & 15, ty = tid >> 4;
    float acc[4][4] = {};
    for (int k0 = 0; k0 < 512; k0 += 64) {
        __syncthreads();
        #pragma unroll
        for (int i = 0; i < 4; ++i) {
            int fid = i * 256 + tid;
            int rr = fid >> 4, c4 = (fid & 15) * 4;
            *(float4*)(As + rr * 68 + c4) = *(const float4*)(A + (size_t)(m0 + rr) * 512 + k0 + c4);
            *(float4*)(Bs + rr * 68 + c4) = *(const float4*)(Bt + (size_t)(n0 + rr) * 512 + k0 + c4);
        }
        __syncthreads();
        #pragma unroll 4
        for (int kk = 0; kk < 64; kk += 4) {
            float4 a4[4], b4[4];
            #pragma unroll
            for (int ii = 0; ii < 4; ++ii) a4[ii] = *(const float4*)(As + (ty + ii * 16) * 68 + kk);
            #pragma unroll
            for (int jjx = 0; jjx < 4; ++jjx) b4[jjx] = *(const float4*)(Bs + (tx + jjx * 16) * 68 + kk);
            #pragma unroll
            for (int ii = 0; ii < 4; ++ii)
                #pragma unroll
                for (int jjx = 0; jjx < 4; ++jjx)
                    acc[ii][jjx] += a4[ii].x * b4[jjx].x + a4[ii].y * b4[jjx].y +
                                    a4[ii].z * b4[jjx].z + a4[ii].w * b4[jjx].w;
        }
    }
    #pragma unroll
    for (int ii = 0; ii < 4; ++ii) {
        int m = m0 + ty + ii * 16;
        #pragma unroll
        for (int jjx = 0; jjx < 4; ++jjx) {
            int n = n0 + tx + jjx * 16;
            float v = acc[ii][jjx] + (bias ? bias[n] : 0.f);
            C[(size_t)m * 512 + n] = v;
        }
    }
}

// ---------------------------------------------------------------------------
// joint: out[m][n] = b_out[n] + sum_k tanh(henc[b,t,k]+hdec[b,u,k]) * Wo[n][k]
// m = b*16384 + t*64 + u; M=65536, N=1024, K=512.
// 128x128 tile, BK=64, f16 MFMA 16x16x32, 4 waves 2x2, 4x4 accs each.
// ---------------------------------------------------------------------------
__global__ void __launch_bounds__(256) k_joint(
        const float* __restrict__ henc, const float* __restrict__ hdec,
        const _Float16* __restrict__ Wo, const float* __restrict__ b_out,
        float* __restrict__ out) {
    __shared__ _Float16 As[128 * 72];
    __shared__ _Float16 Bs[128 * 72];

    const int bn = blockIdx.x & 7;
    const int bm = blockIdx.x >> 3;
    const int m0 = bm * 128, n0 = bn * 128;
    const int b  = m0 >> 14;
    const int t0 = (m0 & 16383) >> 6;

    const int tid  = threadIdx.x;
    const int wave = tid >> 6, lane = tid & 63;
    const int wm = wave >> 1, wn = wave & 1;
    const int l16 = lane & 15, quad = lane >> 4;

    const int r_gen = tid >> 1;
    const int half  = tid & 1;
    const int tg = r_gen >> 6, ug = r_gen & 63;
    const float* he_row = henc + ((size_t)(b * 256 + t0 + tg)) * 512 + half * 32;
    const float* hd_row = hdec + ((size_t)(b * 64 + ug)) * 512 + half * 32;
    _Float16* As_row = As + r_gen * 72 + half * 32;

    f32x4 acc[4][4];
    #pragma unroll
    for (int i = 0; i < 4; ++i)
        #pragma unroll
        for (int jx = 0; jx < 4; ++jx) acc[i][jx] = f32x4{0.f, 0.f, 0.f, 0.f};

    for (int kit = 0; kit < 8; ++kit) {
        const int k0 = kit * 64;
        __syncthreads();
        #pragma unroll
        for (int i2 = 0; i2 < 4; ++i2) {
            float4 a  = *(const float4*)(he_row + k0 + i2 * 8);
            float4 c  = *(const float4*)(hd_row + k0 + i2 * 8);
            float4 a2 = *(const float4*)(he_row + k0 + i2 * 8 + 4);
            float4 c2 = *(const float4*)(hd_row + k0 + i2 * 8 + 4);
            f16x8 z8;
            z8[0] = (_Float16)ftanh(a.x + c.x);
            z8[1] = (_Float16)ftanh(a.y + c.y);
            z8[2] = (_Float16)ftanh(a.z + c.z);
            z8[3] = (_Float16)ftanh(a.w + c.w);
            z8[4] = (_Float16)ftanh(a2.x + c2.x);
            z8[5] = (_Float16)ftanh(a2.y + c2.y);
            z8[6] = (_Float16)ftanh(a2.z + c2.z);
            z8[7] = (_Float16)ftanh(a2.w + c2.w);
            *(f16x8*)(As_row + i2 * 8) = z8;
        }
        #pragma unroll
        for (int j2 = 0; j2 < 4; ++j2) {
            int q = j2 * 256 + tid;
            int rr = q >> 3, c8 = q & 7;
            f16x8 w = *(const f16x8*)(Wo + (size_t)(n0 + rr) * 512 + k0 + c8 * 8);
            *(f16x8*)(Bs + rr * 72 + c8 * 8) = w;
        }
        __syncthreads();
        #pragma unroll
        for (int kk = 0; kk < 64; kk += 32) {
            f16x8 af[4], bfv[4];
            #pragma unroll
            for (int i = 0; i < 4; ++i)
                af[i] = *(const f16x8*)(As + (wm * 64 + i * 16 + l16) * 72 + kk + quad * 8);
            #pragma unroll
            for (int jx = 0; jx < 4; ++jx)
                bfv[jx] = *(const f16x8*)(Bs + (wn * 64 + jx * 16 + l16) * 72 + kk + quad * 8);
            #pragma unroll
            for (int i = 0; i < 4; ++i)
                #pragma unroll
                for (int jx = 0; jx < 4; ++jx)
                    acc[i][jx] = __builtin_amdgcn_mfma_f32_16x16x32_f16(af[i], bfv[jx], acc[i][jx], 0, 0, 0);
        }
    }
    #pragma unroll
    for (int i = 0; i < 4; ++i) {
        int mrow = m0 + wm * 64 + i * 16 + quad * 4;
        #pragma unroll
        for (int jx = 0; jx < 4; ++jx) {
            int col = n0 + wn * 64 + jx * 16 + l16;
            float bo = b_out[col];
            float* po = out + (size_t)mrow * 1024 + col;
            po[0]    = acc[i][jx][0] + bo;
            po[1024] = acc[i][jx][1] + bo;
            po[2048] = acc[i][jx][2] + bo;
            po[3072] = acc[i][jx][3] + bo;
        }
    }
}

// ---------------------------------------------------------------------------
extern "C" void kernel_launch(void* const* d_in, const int* in_sizes, int n_in,
                              void* d_out, int out_size, void* d_ws, size_t ws_size,
                              hipStream_t stream) {
    const float* hs    = (const float*)d_in[0];
    const int*   ys    = (const int*)d_in[2];
    const float* embed = (const float*)d_in[3];
    const float* wih0  = (const float*)d_in[4];
    const float* whh0  = (const float*)d_in[5];
    const float* bih0  = (const float*)d_in[6];
    const float* bhh0  = (const float*)d_in[7];
    const float* wih1  = (const float*)d_in[8];
    const float* whh1  = (const float*)d_in[9];
    const float* bih1  = (const float*)d_in[10];
    const float* bhh1  = (const float*)d_in[11];
    const float* wenc  = (const float*)d_in[12];
    const float* benc  = (const float*)d_in[13];
    const float* wdec  = (const float*)d_in[14];
    const float* wout  = (const float*)d_in[15];
    const float* bout  = (const float*)d_in[16];
    float* out = (float*)d_out;

    char* ws = (char*)d_ws;
    _Float16* WF     = (_Float16*)(ws);                               // 9 MB
    _Float16* Ebuf16 = (_Float16*)(ws + 9u  * 1024 * 1024);           // 256 KB
    float* H0    = (float*)(ws + 9u  * 1024 * 1024 + 512 * 1024);     // 512 KB
    float* H1    = (float*)(ws + 10u * 1024 * 1024);                  // 512 KB
    float* henc  = (float*)(ws + 10u * 1024 * 1024 + 512 * 1024);     // 2 MB
    float* hdec  = (float*)(ws + 12u * 1024 * 1024 + 512 * 1024);     // 512 KB
    int*   flags = (int*)  (ws + 13u * 1024 * 1024);                  // 4 KB

    hipMemsetAsync(flags, 0, 64 * 16 * sizeof(int), stream);
    k_prep_f16<<<2048, 256, 0, stream>>>(wih0, whh0, wih1, whh1, wout, WF, 4718592);
    k_embed<<<256, 256, 0, stream>>>(embed, ys, Ebuf16);
    k_lstm<<<64, 256, 0, stream>>>(WF, bih0, bhh0, bih1, bhh1, Ebuf16, H0, H1, flags);
    k_gemm_small<<<128, 256, 0, stream>>>(hs, wenc, benc, henc);      // M=1024
    k_gemm_small<<<32, 256, 0, stream>>>(H1, wdec, nullptr, hdec);    // M=256
    k_joint<<<4096, 256, 0, stream>>>(henc, hdec, WF + (4u << 20), bout, out);
}